// Round 5
// baseline (293.737 us; speedup 1.0000x reference)
//
#include <hip/hip_runtime.h>
#include <hip/hip_bf16.h>
#include <stdint.h>

// ModulatedConv2d: N=16, IC=OC=256, H=W=64, K=3, STYLE=512. fp32 in/out.
// out = demod[n,oc] * conv2d( x * (1+s)[n,ic], weight )   (StyleGAN2 identity)
// R9: prep collapsed 2 kernels -> 1 (k_prep), killing the prep1->prep2
//     serialization + one ~10us launch gap. Transpose blocks recompute
//     scale[n,:] themselves (style in LDS, thread-per-ic; 256 blocks x 4 rows
//     amortizes it); demod moved into k_conv prologue (per-thread 4 oc values
//     from wsq+scale, hidden under tile-0 staging; loads consumed before the
//     pre-loop VM4 so the counted-vmcnt invariants are untouched). k_conv's
//     R8 core (best measured: 72us, MfmaUtil 44) is byte-identical.

#define NB  16
#define IC  256
#define OC  256
#define HW  64
#define HWP 66
#define SD  512
#define SPATIAL 4096
#define HWPIC 16896   // HWP*IC

typedef __hip_bfloat16 bf16;
typedef __bf16 bf16x8 __attribute__((ext_vector_type(8)));
typedef float  f32x4  __attribute__((ext_vector_type(4)));
typedef uint32_t u32a3 __attribute__((address_space(3)));
typedef const uint32_t u32a1 __attribute__((address_space(1)));

static __device__ __forceinline__ unsigned short f2bu(float f) {
    bf16 h = __float2bfloat16(f);
    union { bf16 b; unsigned short u; } c; c.b = h; return c.u;
}
static __device__ __forceinline__ void gll16(const void* g, void* l) {
    __builtin_amdgcn_global_load_lds((u32a1*)g, (u32a3*)l, 16, 0, 0);
}

// --- P: fused prep, 1040 blocks.
// [0,256):   transpose blocks, (n = b>>4, 4 rows y = (b&15)*4 + 0..3):
//            self-computed scale (no cross-kernel dep), modulate+bf16+NHWC.
// [256,512): weight blocks (oc = b-256): wsq row + wt2.
// [512,1040): zero 1-px border ring of padded NHWC xs.
// All sections independent -> no intra-kernel ordering assumed.
__global__ __launch_bounds__(256)
void k_prep(const float* __restrict__ x, const float* __restrict__ style,
            const float* __restrict__ weight, const float* __restrict__ mod_w,
            const float* __restrict__ mod_b,
            float* __restrict__ wsq, bf16* __restrict__ wt2,
            bf16* __restrict__ xs, uint4* __restrict__ xs4,
            float* __restrict__ scale) {
    __shared__ float sty[SD];                   // 2 KB
    __shared__ float sc[IC];                    // 1 KB
    __shared__ unsigned short tile[HW * 256];   // 32 KB
    int b = blockIdx.x, t = threadIdx.x;
    if (b < 256) {
        int n = b >> 4, yq = b & 15;
        // stage style row, then scale[ic=t] = 1 + style.mod_w[t,:] + mod_b[t]
        sty[t]       = style[n * SD + t];
        sty[t + 256] = style[n * SD + 256 + t];
        __syncthreads();
        {
            const float4* mw4 = (const float4*)mod_w + (size_t)t * 128;
            const float4* st4 = (const float4*)sty;   // broadcast reads
            float a = 0.f;
            #pragma unroll 8
            for (int j = 0; j < 128; ++j) {
                float4 mv = mw4[j], sv = st4[j];
                a += mv.x*sv.x + mv.y*sv.y + mv.z*sv.z + mv.w*sv.w;
            }
            sc[t] = a + mod_b[t] + 1.0f;
            if (yq == 0) scale[n * IC + t] = sc[t];   // persist for k_conv demod
        }
        __syncthreads();
        for (int ry = 0; ry < 4; ++ry) {
            int y = (yq << 2) + ry;
            const float4* xp4 = (const float4*)(x + ((size_t)n * IC) * SPATIAL + (size_t)y * HW);
            #pragma unroll
            for (int i = 0; i < 16; ++i) {
                int fid = i * 256 + t;
                int ic = fid >> 4, f4 = fid & 15;
                float4 v = xp4[(size_t)ic * 1024 + f4];
                float s = sc[ic];
                int sp = f4 << 2;
                int sw = ic ^ ((f4 & 7) << 3);  // XOR-swizzle: <=4-way banks
                tile[(sp + 0) * 256 + sw] = f2bu(v.x * s);
                tile[(sp + 1) * 256 + sw] = f2bu(v.y * s);
                tile[(sp + 2) * 256 + sw] = f2bu(v.z * s);
                tile[(sp + 3) * 256 + sw] = f2bu(v.w * s);
            }
            __syncthreads();
            uint4* dst4 = (uint4*)(xs + (((size_t)n * HWP + (y + 1)) * HWP + 1) * IC);
            #pragma unroll
            for (int j = 0; j < 8; ++j) {
                int uid = j * 256 + t;
                int sp = uid >> 5, g = uid & 31;
                dst4[sp * 32 + g] =
                    *(const uint4*)&tile[sp * 256 + ((g ^ ((sp >> 2) & 7)) << 3)];
            }
            __syncthreads();                    // WAR guard before next row
        }
    } else if (b < 512) {
        // wsq[oc,ic] = sum_r w^2 ; wt2[r][oc][ic] = bf16(w)
        int tid = (b - 256) * 256 + t;
        const float* wp = weight + (size_t)tid * 9;
        float v[9], s = 0.f;
        #pragma unroll
        for (int r = 0; r < 9; ++r) { v[r] = wp[r]; s += v[r] * v[r]; }
        wsq[tid] = s;
        #pragma unroll
        for (int r = 0; r < 9; ++r) wt2[(r << 16) + tid] = __float2bfloat16(v[r]);
    } else {
        // zero 1-px border ring of padded NHWC xs
        int idx = b - 512;
        int n = idx / 33, bx = idx - n * 33;
        int f = bx * 256 + t;
        int u = f >> 5, q = f & 31;
        if (u >= 260) return;
        int rb;
        if      (u <  66) rb = u;
        else if (u < 132) rb = 65 * 66 + (u - 66);
        else if (u < 196) rb = (u - 131) * 66;
        else              rb = (u - 195) * 66 + 65;
        xs4[(size_t)n * 139392 + rb * 32 + q] = make_uint4(0u, 0u, 0u, 0u);
    }
}

// --- K11: implicit-GEMM conv, 256x256 tile, BK=64, 8 waves (2Mx4N), 8-phase,
// 1 barrier/phase, register read-ahead (R8 core, unchanged). Demod computed
// in prologue: each thread derives its own 4 epilogue demod values from
// wsq+scale (loads consumed pre-VM4 -> loop vmcnt invariants unchanged).
#define VM4 asm volatile("s_waitcnt vmcnt(4)" ::: "memory")
#define VM2 asm volatile("s_waitcnt vmcnt(2)" ::: "memory")
#define VM0 asm volatile("s_waitcnt vmcnt(0)" ::: "memory")
#define BAR __builtin_amdgcn_s_barrier()
#define SB0 __builtin_amdgcn_sched_barrier(0)

__global__ __launch_bounds__(512, 2)
void k_conv(const bf16* __restrict__ xs, const bf16* __restrict__ wt2,
            const float* __restrict__ wsq, const float* __restrict__ scale,
            float* __restrict__ out) {
    extern __shared__ char smem[];              // 128 KiB
    int t = threadIdx.x, l = t & 63, w = t >> 6;
    int wm = w & 1, wn = w >> 1;
    int bid = blockIdx.x;
    int work = ((bid & 7) << 5) | (bid >> 3);   // XCD-contiguous: xcd*32 + slot
    int nimg = work >> 4;
    int ybase = (work & 15) << 2;               // 4 image rows per tile
    int spb = (work & 15) << 8;                 // 256 spatial positions

    int srow = (w << 3) + (l >> 3);
    int gseg = (l & 7) ^ (l >> 3);
    const bf16* gA = xs + (((size_t)nimg * HWP + ybase) * HWP + srow) * IC + (gseg << 3);
    const bf16* gB = wt2 + ((size_t)srow << 8) + (gseg << 3);
    int stW = w << 10;                          // wave byte offset in half-tile

    int aRow = ((wm << 6) + (l & 15)) << 7;
    int bRow = ((wn << 5) + (l & 15)) << 7;
    int sg0 = ((l >> 4) ^ (l & 7)) << 4;        // kk=0 swizzled seg
    int sg1 = sg0 ^ 64;                         // kk=1
    int ocol = l & 15;

    f32x4 acc[4][4][2];
    #pragma unroll
    for (int p = 0; p < 4; ++p)
        #pragma unroll
        for (int m = 0; m < 4; ++m)
            #pragma unroll
            for (int n = 0; n < 2; ++n) acc[p][m][n] = (f32x4){0.f, 0.f, 0.f, 0.f};

    bf16x8 afA[4][2], afB[4][2], bf0A[2][2], bf0B[2][2], bf1[2][2];

#define STG_A(ha, PARN, AOFF) do {                                          \
    const bf16* s_ = gA + (AOFF) + (ha) * 2 * HWPIC;                        \
    char* d_ = smem + (PARN) * 32768 + (ha) * 16384 + stW;                  \
    gll16(s_, d_); gll16(s_ + HWPIC, d_ + 8192); } while (0)
#define STG_B(hb, PARN, BOFF) do {                                          \
    const bf16* s_ = gB + (BOFF) + (hb) * (128 * IC);                       \
    char* d_ = smem + 65536 + (PARN) * 32768 + (hb) * 16384 + stW;          \
    gll16(s_, d_); gll16(s_ + 64 * IC, d_ + 8192); } while (0)
#define RD_A(DST, BASE) do { const char* A_ = (const char*)(BASE);          \
    _Pragma("unroll") for (int m_ = 0; m_ < 4; ++m_) {                      \
        DST[m_][0] = *(const bf16x8*)(A_ + m_ * 2048 + sg0);                \
        DST[m_][1] = *(const bf16x8*)(A_ + m_ * 2048 + sg1); } } while (0)
#define RD_B(DST, BASE) do { const char* B_ = (const char*)(BASE);          \
    _Pragma("unroll") for (int n_ = 0; n_ < 2; ++n_) {                      \
        DST[n_][0] = *(const bf16x8*)(B_ + n_ * 2048 + sg0);                \
        DST[n_][1] = *(const bf16x8*)(B_ + n_ * 2048 + sg1); } } while (0)
#define MM(P, AF, BF) do {                                                  \
    __builtin_amdgcn_s_setprio(1);                                          \
    _Pragma("unroll") for (int kk_ = 0; kk_ < 2; ++kk_)                     \
    _Pragma("unroll") for (int m_ = 0; m_ < 4; ++m_)                        \
    _Pragma("unroll") for (int n_ = 0; n_ < 2; ++n_)                        \
        acc[P][m_][n_] = __builtin_amdgcn_mfma_f32_16x16x32_bf16(           \
            AF[m_][kk_], BF[n_][kk_], acc[P][m_][n_], 0, 0, 0);             \
    __builtin_amdgcn_s_setprio(0); } while (0)

#define TILE(PAR, BF0C, BF0N, AOFF1, BOFF1) do {                            \
    const char* Ap_  = smem + (PAR) * 32768;                                \
    const char* Bp_  = smem + 65536 + (PAR) * 32768;                        \
    const char* Apn_ = smem + ((PAR) ^ 1) * 32768;                          \
    const char* Bpn_ = smem + 65536 + ((PAR) ^ 1) * 32768;                  \
    STG_A(0, (PAR) ^ 1, AOFF1);                                             \
    VM4; BAR;                                                               \
    RD_B(bf1, Bp_ + 16384 + bRow);                                          \
    SB0;                                                                    \
    MM(0, afA, BF0C);                                                       \
    STG_B(0, (PAR) ^ 1, BOFF1);                                             \
    VM4; BAR;                                                               \
    RD_A(afB, Ap_ + 16384 + aRow);                                          \
    SB0;                                                                    \
    MM(1, afA, bf1);                                                        \
    STG_B(1, (PAR) ^ 1, BOFF1);                                             \
    BAR;                                                                    \
    MM(2, afB, bf1);                                                        \
    STG_A(1, (PAR) ^ 1, AOFF1);                                             \
    VM4; BAR;                                                               \
    RD_A(afA, Apn_ + aRow);                                                 \
    RD_B(BF0N, Bpn_ + bRow);                                                \
    SB0;                                                                    \
    MM(3, afB, BF0C);                                                       \
} while (0)

    // prologue: stage tile 0 (A0,B0,B1,A1)
    STG_A(0, 0, 0);
    STG_B(0, 0, 0);
    STG_B(1, 0, 0);
    STG_A(1, 0, 0);

    // demod for this thread's 4 epilogue oc values, overlapped with staging.
    // All loads are consumed here (before VM4) -> entering the loop at least
    // as drained as R8; counted-vmcnt invariants unchanged.
    float dmv[2][2];
    {
        const float4* scg  = (const float4*)(scale + (size_t)nimg * IC);
        const float4* wq00 = (const float4*)(wsq + (size_t)((wn << 5) + ocol) * IC);
        const float4* wq01 = (const float4*)(wsq + (size_t)((wn << 5) + 16 + ocol) * IC);
        const float4* wq10 = (const float4*)(wsq + (size_t)(128 + (wn << 5) + ocol) * IC);
        const float4* wq11 = (const float4*)(wsq + (size_t)(128 + (wn << 5) + 16 + ocol) * IC);
        float a00 = 0.f, a01 = 0.f, a10 = 0.f, a11 = 0.f;
        #pragma unroll 8
        for (int i = 0; i < 64; ++i) {
            float4 s = scg[i];
            float sx = s.x*s.x, sy = s.y*s.y, sz = s.z*s.z, sw = s.w*s.w;
            float4 q;
            q = wq00[i]; a00 += q.x*sx + q.y*sy + q.z*sz + q.w*sw;
            q = wq01[i]; a01 += q.x*sx + q.y*sy + q.z*sz + q.w*sw;
            q = wq10[i]; a10 += q.x*sx + q.y*sy + q.z*sz + q.w*sw;
            q = wq11[i]; a11 += q.x*sx + q.y*sy + q.z*sz + q.w*sw;
        }
        dmv[0][0] = rsqrtf(a00 + 1e-8f);
        dmv[0][1] = rsqrtf(a01 + 1e-8f);
        dmv[1][0] = rsqrtf(a10 + 1e-8f);
        dmv[1][1] = rsqrtf(a11 + 1e-8f);
    }

    VM4;
    BAR;
    RD_A(afA, smem + aRow);
    RD_B(bf0A, smem + 65536 + bRow);

    #pragma clang loop unroll(disable)
    for (int TT = 0; TT < 17; ++TT) {
        int Tn1 = 2 * TT + 1, Tn2 = 2 * TT + 2;
        int r1 = Tn1 >> 2, ic1 = (Tn1 & 3) << 6;
        int ky1 = r1 / 3, kx1 = r1 - ky1 * 3;
        int aoff1 = (ky1 * HWP + kx1) * IC + ic1, boff1 = (r1 << 16) + ic1;
        int r2 = Tn2 >> 2, ic2 = (Tn2 & 3) << 6;
        int ky2 = r2 / 3, kx2 = r2 - ky2 * 3;
        int aoff2 = (ky2 * HWP + kx2) * IC + ic2, boff2 = (r2 << 16) + ic2;
        TILE(0, bf0A, bf0B, aoff1, boff1);      // even tile, cur bf0A
        TILE(1, bf0B, bf0A, aoff2, boff2);      // odd tile, cur bf0B
    }
    {   // tile 34 (par 0): stages tile 35 (r=8, ic=192)
        int aoff35 = (2 * HWP + 2) * IC + 192, boff35 = (8 << 16) + 192;
        TILE(0, bf0A, bf0B, aoff35, boff35);
    }
    {   // tile 35 tail (par 1, cur bf0B): no staging; drains 2->0
        const char* Ap_ = smem + 32768;
        const char* Bp_ = smem + 65536 + 32768;
        VM2; BAR;
        RD_B(bf1, Bp_ + 16384 + bRow);
        SB0;
        MM(0, afA, bf0B);
        VM0; BAR;
        RD_A(afB, Ap_ + 16384 + aRow);
        SB0;
        MM(1, afA, bf1);
        MM(2, afB, bf1);
        MM(3, afB, bf0B);
    }

    // epilogue: D[row=(l>>4)*4+v][col=l&15]; 16B stores along spatial
    int orow = (l >> 4) << 2;
    #pragma unroll
    for (int p = 0; p < 4; ++p) {
        int qa = p >> 1, qb = qa ^ (p & 1);     // (0,0)(0,1)(1,1)(1,0)
        #pragma unroll
        for (int n = 0; n < 2; ++n) {
            int oc = (qb << 7) + (wn << 5) + (n << 4) + ocol;
            float d = dmv[qb][n];
            size_t ob = ((size_t)(nimg * OC + oc)) * SPATIAL
                      + spb + (qa << 7) + (wm << 6) + orow;
            #pragma unroll
            for (int m = 0; m < 4; ++m) {
                f32x4 a = acc[p][m][n];
                f32x4 o = { a[0] * d, a[1] * d, a[2] * d, a[3] * d };
                *reinterpret_cast<f32x4*>(out + ob + m * 16) = o;
            }
        }
    }
}

extern "C" void kernel_launch(void* const* d_in, const int* in_sizes, int n_in,
                              void* d_out, int out_size, void* d_ws, size_t ws_size,
                              hipStream_t stream) {
    const float* x      = (const float*)d_in[0];
    const float* style  = (const float*)d_in[1];
    const float* weight = (const float*)d_in[2];
    const float* mod_w  = (const float*)d_in[3];
    const float* mod_b  = (const float*)d_in[4];
    float* out = (float*)d_out;

    char* ws = (char*)d_ws;                  // ~37.2 MB
    float* scale = (float*)(ws + 0);         // 16 KB
    float* wsq   = (float*)(ws + 32768);     // 256 KB
    bf16*  wt2   = (bf16*)(ws + 294912);     // 1.18 MB [r][oc][ic]
    bf16*  xs    = (bf16*)(ws + 1474560);    // 35.7 MB padded NHWC

    static int s_attr = 0;
    if (!s_attr) {
        hipFuncSetAttribute(reinterpret_cast<const void*>(k_conv),
                            hipFuncAttributeMaxDynamicSharedMemorySize, 131072);
        s_attr = 1;
    }

    k_prep<<<1040, 256, 0, stream>>>(x, style, weight, mod_w, mod_b,
                                     wsq, wt2, xs, (uint4*)xs, scale);
    k_conv<<<256, 512, 131072, stream>>>(xs, wt2, wsq, scale, out);
}

// Round 6
// 253.485 us; speedup vs baseline: 1.1588x; 1.1588x over previous
//
#include <hip/hip_runtime.h>
#include <hip/hip_bf16.h>
#include <hip/hip_cooperative_groups.h>
#include <stdint.h>

// ModulatedConv2d: N=16, IC=OC=256, H=W=64, K=3, STYLE=512. fp32 in/out.
// out = demod[n,oc] * conv2d( x * (1+s)[n,ic], weight )   (StyleGAN2 identity)
// R10: ONE cooperative kernel (256 blocks x 512 thr = 1 block/CU, guaranteed
//      co-resident; grid.sync() between phases) -> zero launch gaps.
//      Work-conserving prep (R9 lesson): scale = one wave per (n,ic) shuffle
//      dot (mod_w read ~once); demod = 32 lanes per (n,oc), wsq read once;
//      transpose = block-per-4-rows as R8. Conv phase = R8's 72us core,
//      byte-identical schedule; demod loaded in EPILOGUE (post-VM0) so the
//      counted-vmcnt loop invariants are untouched.

#define NB  16
#define IC  256
#define OC  256
#define HW  64
#define HWP 66
#define SD  512
#define SPATIAL 4096
#define HWPIC 16896   // HWP*IC

typedef __hip_bfloat16 bf16;
typedef __bf16 bf16x8 __attribute__((ext_vector_type(8)));
typedef float  f32x4  __attribute__((ext_vector_type(4)));
typedef uint32_t u32a3 __attribute__((address_space(3)));
typedef const uint32_t u32a1 __attribute__((address_space(1)));

static __device__ __forceinline__ unsigned short f2bu(float f) {
    bf16 h = __float2bfloat16(f);
    union { bf16 b; unsigned short u; } c; c.b = h; return c.u;
}
static __device__ __forceinline__ void gll16(const void* g, void* l) {
    __builtin_amdgcn_global_load_lds((u32a1*)g, (u32a3*)l, 16, 0, 0);
}

#define VM4 asm volatile("s_waitcnt vmcnt(4)" ::: "memory")
#define VM2 asm volatile("s_waitcnt vmcnt(2)" ::: "memory")
#define VM0 asm volatile("s_waitcnt vmcnt(0)" ::: "memory")
#define BAR __builtin_amdgcn_s_barrier()
#define SB0 __builtin_amdgcn_sched_barrier(0)

__global__ __launch_bounds__(512, 2)
void k_fused(const float* __restrict__ x, const float* __restrict__ style,
             const float* __restrict__ weight, const float* __restrict__ mod_w,
             const float* __restrict__ mod_b,
             float* __restrict__ wsq, bf16* __restrict__ wt2,
             bf16* __restrict__ xs, float* __restrict__ scale,
             float* __restrict__ demod_g, float* __restrict__ out) {
    extern __shared__ char smem[];              // 128 KiB
    int b = blockIdx.x, t = threadIdx.x;
    int l = t & 63, w = t >> 6;

    // ---------------- Phase A1: weight, border, scale -----------------------
    // A1a: wsq[oc=b, ic=t] + wt2[r][b][t]  (t<256)
    if (t < 256) {
        int tid = (b << 8) + t;
        const float* wp = weight + (size_t)tid * 9;
        float v[9], s = 0.f;
        #pragma unroll
        for (int r = 0; r < 9; ++r) { v[r] = wp[r]; s += v[r] * v[r]; }
        wsq[tid] = s;
        #pragma unroll
        for (int r = 0; r < 9; ++r) wt2[(r << 16) + tid] = __float2bfloat16(v[r]);
    }
    // A1b: zero 1-px border ring of padded NHWC xs. 133120 flat tasks.
    {
        uint4* xs4 = (uint4*)xs;
        #pragma unroll
        for (int rep = 0; rep < 2; ++rep) {
            int g2 = (b << 9) + t + rep * 131072;
            if (g2 < 133120) {
                int n = g2 / 8320, rem = g2 - n * 8320;
                int u = rem >> 5, q = rem & 31;
                int rb;
                if      (u <  66) rb = u;
                else if (u < 132) rb = 65 * 66 + (u - 66);
                else if (u < 196) rb = (u - 131) * 66;
                else              rb = (u - 195) * 66 + 65;
                xs4[(size_t)n * 139392 + rb * 32 + q] = make_uint4(0u, 0u, 0u, 0u);
            }
        }
    }
    // A1c: scale[n,ic] = 1 + style[n,:].mod_w[ic,:] + mod_b[ic].
    // One wave per output, 2 outputs per wave (2048 waves, 4096 outputs).
    {
        int wid = (b << 3) + w;
        #pragma unroll
        for (int k = 0; k < 2; ++k) {
            int task = (wid << 1) + k;
            int n = task >> 8, ic = task & 255;
            const float4* mw4 = (const float4*)mod_w + (size_t)ic * 128 + l * 2;
            const float4* st4 = (const float4*)style + (size_t)n * 128 + l * 2;
            float4 a0 = mw4[0], a1 = mw4[1], s0 = st4[0], s1 = st4[1];
            float acc = a0.x*s0.x + a0.y*s0.y + a0.z*s0.z + a0.w*s0.w
                      + a1.x*s1.x + a1.y*s1.y + a1.z*s1.z + a1.w*s1.w;
            #pragma unroll
            for (int off = 32; off > 0; off >>= 1) acc += __shfl_down(acc, off);
            if (l == 0) scale[task] = acc + mod_b[ic] + 1.0f;
        }
    }

    cooperative_groups::this_grid().sync();

    // ---------------- Phase A2: modulate+transpose (4 rows) + demod ---------
    {
        unsigned short* tile = (unsigned short*)smem;       // 32 KB
        float* scL = (float*)(smem + 32768);                // 1 KB
        int n = b >> 4, yq = b & 15;
        if (t < 64) ((float4*)scL)[t] = ((const float4*)(scale + (size_t)n * IC))[t];
        __syncthreads();
        for (int ry = 0; ry < 4; ++ry) {
            int y = (yq << 2) + ry;
            const float4* xp4 = (const float4*)(x + ((size_t)n * IC) * SPATIAL + (size_t)y * HW);
            #pragma unroll
            for (int i = 0; i < 8; ++i) {
                int fid = i * 512 + t;
                int ic = fid >> 4, f4 = fid & 15;
                float4 v = xp4[(size_t)ic * 1024 + f4];
                float s = scL[ic];
                int sp = f4 << 2;
                int sw = ic ^ ((f4 & 7) << 3);  // XOR-swizzle: <=4-way banks
                tile[(sp + 0) * 256 + sw] = f2bu(v.x * s);
                tile[(sp + 1) * 256 + sw] = f2bu(v.y * s);
                tile[(sp + 2) * 256 + sw] = f2bu(v.z * s);
                tile[(sp + 3) * 256 + sw] = f2bu(v.w * s);
            }
            __syncthreads();
            uint4* dst4 = (uint4*)(xs + (((size_t)n * HWP + (y + 1)) * HWP + 1) * IC);
            #pragma unroll
            for (int j = 0; j < 4; ++j) {
                int uid = j * 512 + t;
                int sp = uid >> 5, g = uid & 31;
                dst4[sp * 32 + g] =
                    *(const uint4*)&tile[sp * 256 + ((g ^ ((sp >> 2) & 7)) << 3)];
            }
            __syncthreads();                    // WAR guard before next row
        }
        // demod[n, yq*16+g] = rsqrt( sum_ic wsq[oc,ic]*scL[ic]^2 + eps )
        // 32 lanes per oc; wsq read exactly once across the grid.
        {
            int g = t >> 5, lane32 = t & 31;
            int oc = (yq << 4) + g;
            const float4* wq = (const float4*)(wsq + (size_t)oc * IC) + lane32 * 2;
            const float4* sq = (const float4*)scL + lane32 * 2;
            float4 q0 = wq[0], q1 = wq[1], s0 = sq[0], s1 = sq[1];
            float a = q0.x*s0.x*s0.x + q0.y*s0.y*s0.y + q0.z*s0.z*s0.z + q0.w*s0.w*s0.w
                    + q1.x*s1.x*s1.x + q1.y*s1.y*s1.y + q1.z*s1.z*s1.z + q1.w*s1.w*s1.w;
            #pragma unroll
            for (int off = 16; off > 0; off >>= 1) a += __shfl_down(a, off, 32);
            if (lane32 == 0) demod_g[n * OC + oc] = rsqrtf(a + 1e-8f);
        }
    }

    cooperative_groups::this_grid().sync();
    VM0;    // clean vmem slate: conv's counted-vmcnt assumes 0 outstanding

    // ---------------- Phase B: conv (R8 core, byte-identical schedule) ------
    int wm = w & 1, wn = w >> 1;
    int work = ((b & 7) << 5) | (b >> 3);       // XCD-contiguous: xcd*32 + slot
    int nimg = work >> 4;
    int ybase = (work & 15) << 2;               // 4 image rows per tile
    int spb = (work & 15) << 8;                 // 256 spatial positions

    int srow = (w << 3) + (l >> 3);
    int gseg = (l & 7) ^ (l >> 3);
    const bf16* gA = xs + (((size_t)nimg * HWP + ybase) * HWP + srow) * IC + (gseg << 3);
    const bf16* gB = wt2 + ((size_t)srow << 8) + (gseg << 3);
    int stW = w << 10;                          // wave byte offset in half-tile

    int aRow = ((wm << 6) + (l & 15)) << 7;
    int bRow = ((wn << 5) + (l & 15)) << 7;
    int sg0 = ((l >> 4) ^ (l & 7)) << 4;        // kk=0 swizzled seg
    int sg1 = sg0 ^ 64;                         // kk=1
    int ocol = l & 15;

    f32x4 acc[4][4][2];
    #pragma unroll
    for (int p = 0; p < 4; ++p)
        #pragma unroll
        for (int m = 0; m < 4; ++m)
            #pragma unroll
            for (int n = 0; n < 2; ++n) acc[p][m][n] = (f32x4){0.f, 0.f, 0.f, 0.f};

    bf16x8 afA[4][2], afB[4][2], bf0A[2][2], bf0B[2][2], bf1[2][2];

#define STG_A(ha, PARN, AOFF) do {                                          \
    const bf16* s_ = gA + (AOFF) + (ha) * 2 * HWPIC;                        \
    char* d_ = smem + (PARN) * 32768 + (ha) * 16384 + stW;                  \
    gll16(s_, d_); gll16(s_ + HWPIC, d_ + 8192); } while (0)
#define STG_B(hb, PARN, BOFF) do {                                          \
    const bf16* s_ = gB + (BOFF) + (hb) * (128 * IC);                       \
    char* d_ = smem + 65536 + (PARN) * 32768 + (hb) * 16384 + stW;          \
    gll16(s_, d_); gll16(s_ + 64 * IC, d_ + 8192); } while (0)
#define RD_A(DST, BASE) do { const char* A_ = (const char*)(BASE);          \
    _Pragma("unroll") for (int m_ = 0; m_ < 4; ++m_) {                      \
        DST[m_][0] = *(const bf16x8*)(A_ + m_ * 2048 + sg0);                \
        DST[m_][1] = *(const bf16x8*)(A_ + m_ * 2048 + sg1); } } while (0)
#define RD_B(DST, BASE) do { const char* B_ = (const char*)(BASE);          \
    _Pragma("unroll") for (int n_ = 0; n_ < 2; ++n_) {                      \
        DST[n_][0] = *(const bf16x8*)(B_ + n_ * 2048 + sg0);                \
        DST[n_][1] = *(const bf16x8*)(B_ + n_ * 2048 + sg1); } } while (0)
#define MM(P, AF, BF) do {                                                  \
    __builtin_amdgcn_s_setprio(1);                                          \
    _Pragma("unroll") for (int kk_ = 0; kk_ < 2; ++kk_)                     \
    _Pragma("unroll") for (int m_ = 0; m_ < 4; ++m_)                        \
    _Pragma("unroll") for (int n_ = 0; n_ < 2; ++n_)                        \
        acc[P][m_][n_] = __builtin_amdgcn_mfma_f32_16x16x32_bf16(           \
            AF[m_][kk_], BF[n_][kk_], acc[P][m_][n_], 0, 0, 0);             \
    __builtin_amdgcn_s_setprio(0); } while (0)

#define TILE(PAR, BF0C, BF0N, AOFF1, BOFF1) do {                            \
    const char* Ap_  = smem + (PAR) * 32768;                                \
    const char* Bp_  = smem + 65536 + (PAR) * 32768;                        \
    const char* Apn_ = smem + ((PAR) ^ 1) * 32768;                          \
    const char* Bpn_ = smem + 65536 + ((PAR) ^ 1) * 32768;                  \
    STG_A(0, (PAR) ^ 1, AOFF1);                                             \
    VM4; BAR;                                                               \
    RD_B(bf1, Bp_ + 16384 + bRow);                                          \
    SB0;                                                                    \
    MM(0, afA, BF0C);                                                       \
    STG_B(0, (PAR) ^ 1, BOFF1);                                             \
    VM4; BAR;                                                               \
    RD_A(afB, Ap_ + 16384 + aRow);                                          \
    SB0;                                                                    \
    MM(1, afA, bf1);                                                        \
    STG_B(1, (PAR) ^ 1, BOFF1);                                             \
    BAR;                                                                    \
    MM(2, afB, bf1);                                                        \
    STG_A(1, (PAR) ^ 1, AOFF1);                                             \
    VM4; BAR;                                                               \
    RD_A(afA, Apn_ + aRow);                                                 \
    RD_B(BF0N, Bpn_ + bRow);                                                \
    SB0;                                                                    \
    MM(3, afB, BF0C);                                                       \
} while (0)

    // prologue: stage tile 0 (A0,B0,B1,A1)
    STG_A(0, 0, 0);
    STG_B(0, 0, 0);
    STG_B(1, 0, 0);
    STG_A(1, 0, 0);
    VM4;
    BAR;
    RD_A(afA, smem + aRow);
    RD_B(bf0A, smem + 65536 + bRow);

    #pragma clang loop unroll(disable)
    for (int TT = 0; TT < 17; ++TT) {
        int Tn1 = 2 * TT + 1, Tn2 = 2 * TT + 2;
        int r1 = Tn1 >> 2, ic1 = (Tn1 & 3) << 6;
        int ky1 = r1 / 3, kx1 = r1 - ky1 * 3;
        int aoff1 = (ky1 * HWP + kx1) * IC + ic1, boff1 = (r1 << 16) + ic1;
        int r2 = Tn2 >> 2, ic2 = (Tn2 & 3) << 6;
        int ky2 = r2 / 3, kx2 = r2 - ky2 * 3;
        int aoff2 = (ky2 * HWP + kx2) * IC + ic2, boff2 = (r2 << 16) + ic2;
        TILE(0, bf0A, bf0B, aoff1, boff1);      // even tile, cur bf0A
        TILE(1, bf0B, bf0A, aoff2, boff2);      // odd tile, cur bf0B
    }
    {   // tile 34 (par 0): stages tile 35 (r=8, ic=192)
        int aoff35 = (2 * HWP + 2) * IC + 192, boff35 = (8 << 16) + 192;
        TILE(0, bf0A, bf0B, aoff35, boff35);
    }
    {   // tile 35 tail (par 1, cur bf0B): no staging; drains 2->0
        const char* Ap_ = smem + 32768;
        const char* Bp_ = smem + 65536 + 32768;
        VM2; BAR;
        RD_B(bf1, Bp_ + 16384 + bRow);
        SB0;
        MM(0, afA, bf0B);
        VM0; BAR;
        RD_A(afB, Ap_ + 16384 + aRow);
        SB0;
        MM(1, afA, bf1);
        MM(2, afB, bf1);
        MM(3, afB, bf0B);
    }

    // epilogue: demod loaded HERE (post-VM0; loop vmcnt accounting untouched)
    float dmv[2][2];
    #pragma unroll
    for (int qb = 0; qb < 2; ++qb)
        #pragma unroll
        for (int nn = 0; nn < 2; ++nn)
            dmv[qb][nn] = demod_g[nimg * OC + (qb << 7) + (wn << 5) + (nn << 4) + ocol];

    int orow = (l >> 4) << 2;
    #pragma unroll
    for (int p = 0; p < 4; ++p) {
        int qa = p >> 1, qb = qa ^ (p & 1);     // (0,0)(0,1)(1,1)(1,0)
        #pragma unroll
        for (int n = 0; n < 2; ++n) {
            int oc = (qb << 7) + (wn << 5) + (n << 4) + ocol;
            float d = dmv[qb][n];
            size_t ob = ((size_t)(nimg * OC + oc)) * SPATIAL
                      + spb + (qa << 7) + (wm << 6) + orow;
            #pragma unroll
            for (int m = 0; m < 4; ++m) {
                f32x4 a = acc[p][m][n];
                f32x4 o = { a[0] * d, a[1] * d, a[2] * d, a[3] * d };
                *reinterpret_cast<f32x4*>(out + ob + m * 16) = o;
            }
        }
    }
}

extern "C" void kernel_launch(void* const* d_in, const int* in_sizes, int n_in,
                              void* d_out, int out_size, void* d_ws, size_t ws_size,
                              hipStream_t stream) {
    const float* x      = (const float*)d_in[0];
    const float* style  = (const float*)d_in[1];
    const float* weight = (const float*)d_in[2];
    const float* mod_w  = (const float*)d_in[3];
    const float* mod_b  = (const float*)d_in[4];
    float* out = (float*)d_out;

    char* ws = (char*)d_ws;                  // ~37.2 MB
    float* scale = (float*)(ws + 0);         // 16 KB
    float* demod = (float*)(ws + 16384);     // 16 KB
    float* wsq   = (float*)(ws + 32768);     // 256 KB
    bf16*  wt2   = (bf16*)(ws + 294912);     // 1.18 MB [r][oc][ic]
    bf16*  xs    = (bf16*)(ws + 1474560);    // 35.7 MB padded NHWC

    static int s_attr = 0;
    if (!s_attr) {
        hipFuncSetAttribute(reinterpret_cast<const void*>(k_fused),
                            hipFuncAttributeMaxDynamicSharedMemorySize, 131072);
        s_attr = 1;
    }

    void* kargs[] = { (void*)&x, (void*)&style, (void*)&weight, (void*)&mod_w,
                      (void*)&mod_b, (void*)&wsq, (void*)&wt2, (void*)&xs,
                      (void*)&scale, (void*)&demod, (void*)&out };
    hipLaunchCooperativeKernel(reinterpret_cast<void*>(k_fused),
                               dim3(256), dim3(512), kargs, 131072, stream);
}

// Round 7
// 221.615 us; speedup vs baseline: 1.3254x; 1.1438x over previous
//
#include <hip/hip_runtime.h>
#include <hip/hip_bf16.h>
#include <stdint.h>

// ModulatedConv2d: N=16, IC=OC=256, H=W=64, K=3, STYLE=512. fp32 in/out.
// out = demod[n,oc] * conv2d( x * (1+s)[n,ic], weight )   (StyleGAN2 identity)
// R11: two captured launches (R10 proved cooperative = +107us overhead).
//      ONE work-conserving prep kernel: transpose blocks recompute scale
//      internally (coalesced wave-dots, ~1us, 2x-redundant L2 mod_w reads —
//      NOT R9's serial-dot); weight + border sections unchanged; all sections
//      independent (no intra-kernel ordering). demod moved to k_conv EPILOGUE,
//      cooperative (wsq read once per block, LDS pair-reduce) — entirely
//      post-VM0 so the verified 72us counted-vmcnt loop is byte-identical.

#define NB  16
#define IC  256
#define OC  256
#define HW  64
#define HWP 66
#define SD  512
#define SPATIAL 4096
#define HWPIC 16896   // HWP*IC

typedef __hip_bfloat16 bf16;
typedef __bf16 bf16x8 __attribute__((ext_vector_type(8)));
typedef float  f32x4  __attribute__((ext_vector_type(4)));
typedef uint32_t u32a3 __attribute__((address_space(3)));
typedef const uint32_t u32a1 __attribute__((address_space(1)));

static __device__ __forceinline__ unsigned short f2bu(float f) {
    bf16 h = __float2bfloat16(f);
    union { bf16 b; unsigned short u; } c; c.b = h; return c.u;
}
static __device__ __forceinline__ void gll16(const void* g, void* l) {
    __builtin_amdgcn_global_load_lds((u32a1*)g, (u32a3*)l, 16, 0, 0);
}

// --- P: fused prep, 1296 blocks x 256 thr. All sections independent.
// [0,512):    transpose blocks: n = b>>5, 2 rows y = (b&31)*2 + {0,1}.
//             scale recomputed in-block via wave-dots; yq==0 persists it.
// [512,768):  weight blocks (oc = b-512): wsq row + wt2 (unmodulated).
// [768,1296): zero 1-px border ring of padded NHWC xs.
__global__ __launch_bounds__(256)
void k_prep(const float* __restrict__ x, const float* __restrict__ style,
            const float* __restrict__ weight, const float* __restrict__ mod_w,
            const float* __restrict__ mod_b,
            float* __restrict__ wsq, bf16* __restrict__ wt2,
            bf16* __restrict__ xs, uint4* __restrict__ xs4,
            float* __restrict__ scale) {
    __shared__ unsigned short tile[HW * 256];   // 32 KB
    __shared__ float sc[IC];                    // 1 KB
    int b = blockIdx.x, t = threadIdx.x;
    if (b < 512) {
        int n = b >> 5, yq = b & 31;
        int l = t & 63, w = t >> 6;
        // scale[ic] = 1 + style[n,:].mod_w[ic,:] + mod_b[ic]; wave w owns
        // ic in [w*64, w*64+64), 4 dots per round (ILP), coalesced 2KB rows.
        const float4* st4 = (const float4*)style + (size_t)n * 128 + (l << 1);
        float4 s0 = st4[0], s1 = st4[1];
        for (int g = 0; g < 16; ++g) {
            float av[4];
            #pragma unroll
            for (int k = 0; k < 4; ++k) {
                int ic = (w << 6) + (g << 2) + k;
                const float4* mw4 = (const float4*)mod_w + (size_t)ic * 128 + (l << 1);
                float4 a0 = mw4[0], a1 = mw4[1];
                av[k] = a0.x*s0.x + a0.y*s0.y + a0.z*s0.z + a0.w*s0.w
                      + a1.x*s1.x + a1.y*s1.y + a1.z*s1.z + a1.w*s1.w;
            }
            #pragma unroll
            for (int k = 0; k < 4; ++k) {
                float a = av[k];
                #pragma unroll
                for (int off = 32; off > 0; off >>= 1) a += __shfl_down(a, off);
                if (l == 0) {
                    int ic = (w << 6) + (g << 2) + k;
                    float v = a + mod_b[ic] + 1.0f;
                    sc[ic] = v;
                    if (yq == 0) scale[(n << 8) + ic] = v;  // persist for conv
                }
            }
        }
        __syncthreads();
        for (int ry = 0; ry < 2; ++ry) {
            int y = (yq << 1) + ry;
            const float4* xp4 = (const float4*)(x + ((size_t)n * IC) * SPATIAL + (size_t)y * HW);
            #pragma unroll
            for (int i = 0; i < 16; ++i) {
                int fid = i * 256 + t;
                int ic = fid >> 4, f4 = fid & 15;
                float4 v = xp4[(size_t)ic * 1024 + f4];
                float s = sc[ic];
                int sp = f4 << 2;
                int sw = ic ^ ((f4 & 7) << 3);  // XOR-swizzle: <=4-way banks
                tile[(sp + 0) * 256 + sw] = f2bu(v.x * s);
                tile[(sp + 1) * 256 + sw] = f2bu(v.y * s);
                tile[(sp + 2) * 256 + sw] = f2bu(v.z * s);
                tile[(sp + 3) * 256 + sw] = f2bu(v.w * s);
            }
            __syncthreads();
            uint4* dst4 = (uint4*)(xs + (((size_t)n * HWP + (y + 1)) * HWP + 1) * IC);
            #pragma unroll
            for (int j = 0; j < 8; ++j) {
                int uid = j * 256 + t;
                int sp = uid >> 5, g = uid & 31;
                dst4[sp * 32 + g] =
                    *(const uint4*)&tile[sp * 256 + ((g ^ ((sp >> 2) & 7)) << 3)];
            }
            __syncthreads();                    // WAR guard before next row
        }
    } else if (b < 768) {
        // wsq[oc,ic] = sum_r w^2 ; wt2[r][oc][ic] = bf16(w)
        int tid = ((b - 512) << 8) + t;
        const float* wp = weight + (size_t)tid * 9;
        float v[9], s = 0.f;
        #pragma unroll
        for (int r = 0; r < 9; ++r) { v[r] = wp[r]; s += v[r] * v[r]; }
        wsq[tid] = s;
        #pragma unroll
        for (int r = 0; r < 9; ++r) wt2[(r << 16) + tid] = __float2bfloat16(v[r]);
    } else {
        // zero 1-px border ring of padded NHWC xs
        int idx = b - 768;
        int n = idx / 33, bx = idx - n * 33;
        int f = bx * 256 + t;
        int u = f >> 5, q = f & 31;
        if (u >= 260) return;
        int rb;
        if      (u <  66) rb = u;
        else if (u < 132) rb = 65 * 66 + (u - 66);
        else if (u < 196) rb = (u - 131) * 66;
        else              rb = (u - 195) * 66 + 65;
        xs4[(size_t)n * 139392 + rb * 32 + q] = make_uint4(0u, 0u, 0u, 0u);
    }
}

// --- K12: implicit-GEMM conv, 256x256 tile, BK=64, 8 waves (2Mx4N), 8-phase,
// 1 barrier/phase, register read-ahead (R8 core, byte-identical schedule).
// demod computed cooperatively in the EPILOGUE (post-VM0): thread-pair per oc,
// wsq read once per block, LDS pair-reduce -> 1KB table.
#define VM4 asm volatile("s_waitcnt vmcnt(4)" ::: "memory")
#define VM2 asm volatile("s_waitcnt vmcnt(2)" ::: "memory")
#define VM0 asm volatile("s_waitcnt vmcnt(0)" ::: "memory")
#define BAR __builtin_amdgcn_s_barrier()
#define SB0 __builtin_amdgcn_sched_barrier(0)

__global__ __launch_bounds__(512, 2)
void k_conv(const bf16* __restrict__ xs, const bf16* __restrict__ wt2,
            const float* __restrict__ wsq, const float* __restrict__ scale,
            float* __restrict__ out) {
    extern __shared__ char smem[];              // 128 KiB
    int t = threadIdx.x, l = t & 63, w = t >> 6;
    int wm = w & 1, wn = w >> 1;
    int bid = blockIdx.x;
    int work = ((bid & 7) << 5) | (bid >> 3);   // XCD-contiguous: xcd*32 + slot
    int nimg = work >> 4;
    int ybase = (work & 15) << 2;               // 4 image rows per tile
    int spb = (work & 15) << 8;                 // 256 spatial positions

    int srow = (w << 3) + (l >> 3);
    int gseg = (l & 7) ^ (l >> 3);
    const bf16* gA = xs + (((size_t)nimg * HWP + ybase) * HWP + srow) * IC + (gseg << 3);
    const bf16* gB = wt2 + ((size_t)srow << 8) + (gseg << 3);
    int stW = w << 10;                          // wave byte offset in half-tile

    int aRow = ((wm << 6) + (l & 15)) << 7;
    int bRow = ((wn << 5) + (l & 15)) << 7;
    int sg0 = ((l >> 4) ^ (l & 7)) << 4;        // kk=0 swizzled seg
    int sg1 = sg0 ^ 64;                         // kk=1
    int ocol = l & 15;

    f32x4 acc[4][4][2];
    #pragma unroll
    for (int p = 0; p < 4; ++p)
        #pragma unroll
        for (int m = 0; m < 4; ++m)
            #pragma unroll
            for (int n = 0; n < 2; ++n) acc[p][m][n] = (f32x4){0.f, 0.f, 0.f, 0.f};

    bf16x8 afA[4][2], afB[4][2], bf0A[2][2], bf0B[2][2], bf1[2][2];

#define STG_A(ha, PARN, AOFF) do {                                          \
    const bf16* s_ = gA + (AOFF) + (ha) * 2 * HWPIC;                        \
    char* d_ = smem + (PARN) * 32768 + (ha) * 16384 + stW;                  \
    gll16(s_, d_); gll16(s_ + HWPIC, d_ + 8192); } while (0)
#define STG_B(hb, PARN, BOFF) do {                                          \
    const bf16* s_ = gB + (BOFF) + (hb) * (128 * IC);                       \
    char* d_ = smem + 65536 + (PARN) * 32768 + (hb) * 16384 + stW;          \
    gll16(s_, d_); gll16(s_ + 64 * IC, d_ + 8192); } while (0)
#define RD_A(DST, BASE) do { const char* A_ = (const char*)(BASE);          \
    _Pragma("unroll") for (int m_ = 0; m_ < 4; ++m_) {                      \
        DST[m_][0] = *(const bf16x8*)(A_ + m_ * 2048 + sg0);                \
        DST[m_][1] = *(const bf16x8*)(A_ + m_ * 2048 + sg1); } } while (0)
#define RD_B(DST, BASE) do { const char* B_ = (const char*)(BASE);          \
    _Pragma("unroll") for (int n_ = 0; n_ < 2; ++n_) {                      \
        DST[n_][0] = *(const bf16x8*)(B_ + n_ * 2048 + sg0);                \
        DST[n_][1] = *(const bf16x8*)(B_ + n_ * 2048 + sg1); } } while (0)
#define MM(P, AF, BF) do {                                                  \
    __builtin_amdgcn_s_setprio(1);                                          \
    _Pragma("unroll") for (int kk_ = 0; kk_ < 2; ++kk_)                     \
    _Pragma("unroll") for (int m_ = 0; m_ < 4; ++m_)                        \
    _Pragma("unroll") for (int n_ = 0; n_ < 2; ++n_)                        \
        acc[P][m_][n_] = __builtin_amdgcn_mfma_f32_16x16x32_bf16(           \
            AF[m_][kk_], BF[n_][kk_], acc[P][m_][n_], 0, 0, 0);             \
    __builtin_amdgcn_s_setprio(0); } while (0)

#define TILE(PAR, BF0C, BF0N, AOFF1, BOFF1) do {                            \
    const char* Ap_  = smem + (PAR) * 32768;                                \
    const char* Bp_  = smem + 65536 + (PAR) * 32768;                        \
    const char* Apn_ = smem + ((PAR) ^ 1) * 32768;                          \
    const char* Bpn_ = smem + 65536 + ((PAR) ^ 1) * 32768;                  \
    STG_A(0, (PAR) ^ 1, AOFF1);                                             \
    VM4; BAR;                                                               \
    RD_B(bf1, Bp_ + 16384 + bRow);                                          \
    SB0;                                                                    \
    MM(0, afA, BF0C);                                                       \
    STG_B(0, (PAR) ^ 1, BOFF1);                                             \
    VM4; BAR;                                                               \
    RD_A(afB, Ap_ + 16384 + aRow);                                          \
    SB0;                                                                    \
    MM(1, afA, bf1);                                                        \
    STG_B(1, (PAR) ^ 1, BOFF1);                                             \
    BAR;                                                                    \
    MM(2, afB, bf1);                                                        \
    STG_A(1, (PAR) ^ 1, AOFF1);                                             \
    VM4; BAR;                                                               \
    RD_A(afA, Apn_ + aRow);                                                 \
    RD_B(BF0N, Bpn_ + bRow);                                                \
    SB0;                                                                    \
    MM(3, afB, BF0C);                                                       \
} while (0)

    // prologue: stage tile 0 (A0,B0,B1,A1)
    STG_A(0, 0, 0);
    STG_B(0, 0, 0);
    STG_B(1, 0, 0);
    STG_A(1, 0, 0);
    VM4;
    BAR;
    RD_A(afA, smem + aRow);
    RD_B(bf0A, smem + 65536 + bRow);

    #pragma clang loop unroll(disable)
    for (int TT = 0; TT < 17; ++TT) {
        int Tn1 = 2 * TT + 1, Tn2 = 2 * TT + 2;
        int r1 = Tn1 >> 2, ic1 = (Tn1 & 3) << 6;
        int ky1 = r1 / 3, kx1 = r1 - ky1 * 3;
        int aoff1 = (ky1 * HWP + kx1) * IC + ic1, boff1 = (r1 << 16) + ic1;
        int r2 = Tn2 >> 2, ic2 = (Tn2 & 3) << 6;
        int ky2 = r2 / 3, kx2 = r2 - ky2 * 3;
        int aoff2 = (ky2 * HWP + kx2) * IC + ic2, boff2 = (r2 << 16) + ic2;
        TILE(0, bf0A, bf0B, aoff1, boff1);      // even tile, cur bf0A
        TILE(1, bf0B, bf0A, aoff2, boff2);      // odd tile, cur bf0B
    }
    {   // tile 34 (par 0): stages tile 35 (r=8, ic=192)
        int aoff35 = (2 * HWP + 2) * IC + 192, boff35 = (8 << 16) + 192;
        TILE(0, bf0A, bf0B, aoff35, boff35);
    }
    {   // tile 35 tail (par 1, cur bf0B): no staging; drains 2->0
        const char* Ap_ = smem + 32768;
        const char* Bp_ = smem + 65536 + 32768;
        VM2; BAR;
        RD_B(bf1, Bp_ + 16384 + bRow);
        SB0;
        MM(0, afA, bf0B);
        VM0; BAR;
        RD_A(afB, Ap_ + 16384 + aRow);
        SB0;
        MM(1, afA, bf1);
        MM(2, afB, bf1);
        MM(3, afB, bf0B);
    }

    // ---- epilogue demod (post-VM0; loop vmcnt accounting untouched) --------
    // demod[nimg,oc] = rsqrt( sum_ic wsq[oc,ic]*scale[nimg,ic]^2 + eps ).
    // 2 threads per oc (128 ic each); wsq read once per block; LDS pair-reduce.
    __syncthreads();                            // all frag reads done; smem free
    float* scr = (float*)smem;                  // 512 floats
    float* dmt = scr + 512;                     // 256 floats
    {
        int oc2 = t >> 1, half = t & 1;
        const float4* wq = (const float4*)(wsq + (size_t)oc2 * IC) + (half << 5);
        const float4* sq = (const float4*)(scale + (size_t)nimg * IC) + (half << 5);
        float a = 0.f;
        #pragma unroll 8
        for (int j = 0; j < 32; ++j) {
            float4 q = wq[j], s = sq[j];
            a += q.x*s.x*s.x + q.y*s.y*s.y + q.z*s.z*s.z + q.w*s.w*s.w;
        }
        scr[t] = a;
    }
    __syncthreads();
    if (t < 256) dmt[t] = rsqrtf(scr[2 * t] + scr[2 * t + 1] + 1e-8f);
    __syncthreads();

    float dmv[2][2];
    #pragma unroll
    for (int qb = 0; qb < 2; ++qb)
        #pragma unroll
        for (int nn = 0; nn < 2; ++nn)
            dmv[qb][nn] = dmt[(qb << 7) + (wn << 5) + (nn << 4) + ocol];

    int orow = (l >> 4) << 2;
    #pragma unroll
    for (int p = 0; p < 4; ++p) {
        int qa = p >> 1, qb = qa ^ (p & 1);     // (0,0)(0,1)(1,1)(1,0)
        #pragma unroll
        for (int n = 0; n < 2; ++n) {
            int oc = (qb << 7) + (wn << 5) + (n << 4) + ocol;
            float d = dmv[qb][n];
            size_t ob = ((size_t)(nimg * OC + oc)) * SPATIAL
                      + spb + (qa << 7) + (wm << 6) + orow;
            #pragma unroll
            for (int m = 0; m < 4; ++m) {
                f32x4 a = acc[p][m][n];
                f32x4 o = { a[0] * d, a[1] * d, a[2] * d, a[3] * d };
                *reinterpret_cast<f32x4*>(out + ob + m * 16) = o;
            }
        }
    }
}

extern "C" void kernel_launch(void* const* d_in, const int* in_sizes, int n_in,
                              void* d_out, int out_size, void* d_ws, size_t ws_size,
                              hipStream_t stream) {
    const float* x      = (const float*)d_in[0];
    const float* style  = (const float*)d_in[1];
    const float* weight = (const float*)d_in[2];
    const float* mod_w  = (const float*)d_in[3];
    const float* mod_b  = (const float*)d_in[4];
    float* out = (float*)d_out;

    char* ws = (char*)d_ws;                  // ~37.2 MB
    float* scale = (float*)(ws + 0);         // 16 KB
    float* wsq   = (float*)(ws + 32768);     // 256 KB
    bf16*  wt2   = (bf16*)(ws + 294912);     // 1.18 MB [r][oc][ic]
    bf16*  xs    = (bf16*)(ws + 1474560);    // 35.7 MB padded NHWC

    static int s_attr = 0;
    if (!s_attr) {
        hipFuncSetAttribute(reinterpret_cast<const void*>(k_conv),
                            hipFuncAttributeMaxDynamicSharedMemorySize, 131072);
        s_attr = 1;
    }

    k_prep<<<1296, 256, 0, stream>>>(x, style, weight, mod_w, mod_b,
                                     wsq, wt2, xs, (uint4*)xs, scale);
    k_conv<<<256, 512, 131072, stream>>>(xs, wt2, wsq, scale, out);
}